// Round 5
// baseline (276.370 us; speedup 1.0000x reference)
//
#include <hip/hip_runtime.h>

#define DEV __device__ __forceinline__

constexpr int A_ = 64, DE = 128, M_ = 512, DH = 64;
constexpr int REC = 196;  // partial record: e[128], v[64], max, sum, pad2

DEV float wred_sum64(float v) {
#pragma unroll
    for (int o = 1; o < 64; o <<= 1) v += __shfl_xor(v, o, 64);
    return v;
}
DEV float wred_max64(float v) {
#pragma unroll
    for (int o = 1; o < 64; o <<= 1) v = fmaxf(v, __shfl_xor(v, o, 64));
    return v;
}

// ---------------- Kernel 1: per-(b,m) hyperbolic dH2 + log_map ----------------
__global__ __launch_bounds__(256) void k_hyp(const float* __restrict__ curr_hyp,
                                             const float* __restrict__ demo_hyp,
                                             float* __restrict__ dH2,
                                             float* __restrict__ logv) {
    const int lane = threadIdx.x & 63;
    const int r    = (blockIdx.x << 2) + (threadIdx.x >> 6);  // [0, B*M)
    const int b    = r >> 9;                                  // M=512

    float x = curr_hyp[(b << 6) + lane];
    float y = demo_hyp[((size_t)r << 6) + lane];
    const float mx = 1.0f - 1e-5f;

    float x2r = wred_sum64(x * x);
    float xn  = fmaxf(sqrtf(x2r), 1e-15f);
    float sx  = xn > mx ? mx / xn : 1.0f;
    x *= sx;
    float x2 = x2r * sx * sx;
    float y2r = wred_sum64(y * y);
    float yn  = fmaxf(sqrtf(y2r), 1e-15f);
    float sy  = yn > mx ? mx / yn : 1.0f;
    y *= sy;
    float y2 = y2r * sy * sy;

    float xy = wred_sum64(x * y);
    float num = (1.f - 2.f * xy + y2) * (-x) + (1.f - x2) * y;
    float den = fmaxf(1.f - 2.f * xy + x2 * y2, 1e-15f);
    float u   = num / den;

    float u2  = wred_sum64(u * u);
    float un  = fmaxf(sqrtf(u2), 1e-15f);
    float arg = fminf(un, 1.f - 1e-7f);
    float at  = 0.5f * __logf((1.f + arg) / (1.f - arg));  // atanh

    if (lane == 0) dH2[r] = 4.f * at * at;

    float lamden = fmaxf(1.f - x2, 1e-15f);  // 2/lambda
    float ls     = lamden * at / un;
    logv[((size_t)r << 6) + lane] = ls * u;
}

// ---------------- Kernel 2: split-K partials, contiguous streaming ----------------
// one block per (b, mc); block streams demo[b, mc*8..mc*8+8, :, :] = 256 KB contiguous.
// 512 thr = 8 waves; wave w owns a in [8w, 8w+8) (4 s-pairs x 2 halves).
// half-wave (32 lanes) holds one 512B row: lane dims [4*hl, 4*hl+4).
__global__ __launch_bounds__(512, 4) void k_part(const float* __restrict__ curr_rho,
                                                 const float* __restrict__ demo_rho,
                                                 const float* __restrict__ dH2,
                                                 const float* __restrict__ logv,
                                                 float* __restrict__ part) {
    __shared__ __align__(16) float q_lds[64 * 128];  // 32 KB
    __shared__ __align__(16) float lv_lds[8 * 64];   // 2 KB
    __shared__ float dh_lds[8];

    const int t   = threadIdx.x;
    const int blk = blockIdx.x;
    const int b   = blk >> 6, mc = blk & 63;
    const int lane = t & 63, w = t >> 6;
    const int h = lane >> 5, hl = lane & 31;

    // stage Q (curr_rho[b]: 8192 floats), logv chunk (512), dH2 chunk (8)
    {
        const float* qsrc = curr_rho + (size_t)b * A_ * DE;
#pragma unroll
        for (int i = 0; i < 4; i++)
            *(float4*)&q_lds[i * 2048 + t * 4] = *(const float4*)(qsrc + i * 2048 + t * 4);
        if (t < 128)
            *(float4*)&lv_lds[t * 4] =
                *(const float4*)(logv + ((size_t)b * M_ + mc * 8) * DH + t * 4);
        if (t < 8) dh_lds[t] = dH2[b * M_ + mc * 8 + t];
    }
    __syncthreads();

    // per-s Q fragments: a = 8w + 2s + h
    float qf[4][4];
#pragma unroll
    for (int s = 0; s < 4; s++) {
        int a = 8 * w + 2 * s + h;
        float4 q = *(const float4*)&q_lds[a * 128 + hl * 4];
        qf[s][0] = q.x; qf[s][1] = q.y; qf[s][2] = q.z; qf[s][3] = q.w;
    }

    float mAcc[4], sAcc[4], eAcc[4][4], vAcc[4][2];
#pragma unroll
    for (int s = 0; s < 4; s++) {
        mAcc[s] = -1e30f; sAcc[s] = 0.f;
        eAcc[s][0] = eAcc[s][1] = eAcc[s][2] = eAcc[s][3] = 0.f;
        vAcc[s][0] = vAcc[s][1] = 0.f;
    }

    // wave base: demo[b][mc*8][8w][0]; per-m stride 8192 floats; per-s stride 256 floats
    const float* base = demo_rho + (((size_t)b * M_ + mc * 8) * A_ + 8 * w) * DE;

    float4 cur[4];
#pragma unroll
    for (int s = 0; s < 4; s++) cur[s] = *(const float4*)(base + s * 256 + lane * 4);

    for (int m = 0; m < 8; ++m) {
        float4 nxt[4];
        if (m < 7) {
            const float* nb = base + (size_t)(m + 1) * 8192;
#pragma unroll
            for (int s = 0; s < 4; s++) nxt[s] = *(const float4*)(nb + s * 256 + lane * 4);
        }
        float2 lvv = *(const float2*)&lv_lds[m * 64 + hl * 2];  // halves broadcast
        float dh = dh_lds[m];
#pragma unroll
        for (int s = 0; s < 4; s++) {
            float kf[4] = {cur[s].x, cur[s].y, cur[s].z, cur[s].w};
            float ps = 0.f;
#pragma unroll
            for (int j = 0; j < 4; j++) { float d = qf[s][j] - kf[j]; ps = fmaf(d, d, ps); }
            ps += __shfl_xor(ps, 1, 64);
            ps += __shfl_xor(ps, 2, 64);
            ps += __shfl_xor(ps, 4, 64);
            ps += __shfl_xor(ps, 8, 64);
            ps += __shfl_xor(ps, 16, 64);  // full half-wave sum (offsets < 32 stay in-half)
            float sc = -(dh + ps);

            float nm = fmaxf(mAcc[s], sc);
            float r  = __expf(mAcc[s] - nm);
            float wt = __expf(sc - nm);
            sAcc[s] = sAcc[s] * r + wt;
#pragma unroll
            for (int j = 0; j < 4; j++) eAcc[s][j] = fmaf(eAcc[s][j], r, wt * kf[j]);
            vAcc[s][0] = fmaf(vAcc[s][0], r, wt * lvv.x);
            vAcc[s][1] = fmaf(vAcc[s][1], r, wt * lvv.y);
            mAcc[s] = nm;
        }
#pragma unroll
        for (int s = 0; s < 4; s++) cur[s] = nxt[s];
    }

    // write partial records: part[((b*64 + a)*64 + mc)*REC]
#pragma unroll
    for (int s = 0; s < 4; s++) {
        int a = 8 * w + 2 * s + h;
        float* rec = part + ((size_t)(b * 64 + a) * 64 + mc) * REC;
        *(float4*)(rec + hl * 4) = make_float4(eAcc[s][0], eAcc[s][1], eAcc[s][2], eAcc[s][3]);
        *(float2*)(rec + 128 + hl * 2) = make_float2(vAcc[s][0], vAcc[s][1]);
        if (hl == 0) { rec[192] = mAcc[s]; rec[193] = sAcc[s]; }
    }
}

// ---------------- Kernel 3: merge partials + epilogue ----------------
// one block per (b,a); 256 thr = 4 waves.
__global__ __launch_bounds__(256) void k_merge(const float* __restrict__ part,
                                               const float* __restrict__ curr_hyp,
                                               const float* __restrict__ We,
                                               const float* __restrict__ Wh,
                                               const float* __restrict__ gamma,
                                               const float* __restrict__ beta,
                                               float* __restrict__ out) {
    __shared__ float f_lds[64];
    __shared__ float gsum_s;
    __shared__ float eh[192];  // [0:128) e_out, [128:192) h (after exp-map)
    __shared__ float vv[64];

    const int t = threadIdx.x, w = t >> 6, lane = t & 63;
    const int blk = blockIdx.x, b = blk >> 6;
    const float* pbase = part + (size_t)blk * 64 * REC;

    if (w == 0) {
        float mx = pbase[lane * REC + 192];
        float sm = pbase[lane * REC + 193];
        float g  = wred_max64(mx);
        float f  = __expf(mx - g);
        float gs = wred_sum64(sm * f);
        f_lds[lane] = f;
        if (lane == 0) gsum_s = gs;
    }
    __syncthreads();
    const float inv = 1.f / gsum_s;

    if (t < 192) {
        float acc = 0.f;
#pragma unroll 4
        for (int mc = 0; mc < 64; ++mc) acc = fmaf(pbase[mc * REC + t], f_lds[mc], acc);
        acc *= inv;
        if (t < 128) eh[t] = acc;
        else vv[t - 128] = acc;
    }
    __syncthreads();

    if (w == 0) {
        float v = vv[lane];
        const float mxb = 1.0f - 1e-5f;
        float x = curr_hyp[(b << 6) + lane];
        float x2r = wred_sum64(x * x);
        float xn  = fmaxf(sqrtf(x2r), 1e-15f);
        float sx  = xn > mxb ? mxb / xn : 1.f;
        x *= sx;
        float x2 = x2r * sx * sx;
        float lamden = fmaxf(1.f - x2, 1e-15f);  // 2/lambda

        float v2 = wred_sum64(v * v);
        float vn = fmaxf(sqrtf(v2), 1e-15f);
        float targ   = vn / lamden;              // lambda*vnorm/2
        float e2     = __expf(2.f * targ);
        float factor = 1.f - 2.f / (e2 + 1.f);   // tanh, inf-safe
        float wvv    = v * (factor / vn);

        float w2 = wred_sum64(wvv * wvv);
        float xw = wred_sum64(x * wvv);
        float num = (1.f + 2.f * xw + w2) * x + (1.f - x2) * wvv;
        float den = fmaxf(1.f + 2.f * xw + x2 * w2, 1e-15f);
        float hq  = num / den;
        float h2  = wred_sum64(hq * hq);
        float hn  = fmaxf(sqrtf(h2), 1e-15f);
        float shh = hn > mxb ? mxb / hn : 1.f;
        hq *= shh;
        eh[128 + lane] = hq;  // same-wave visibility

        float ze = 0.f;
        const float* werow = We + lane * 128;
#pragma unroll
        for (int d0 = 0; d0 < 128; d0 += 4) {
            float4 wv4 = *(const float4*)(werow + d0);
            ze = fmaf(eh[d0 + 0], wv4.x, ze);
            ze = fmaf(eh[d0 + 1], wv4.y, ze);
            ze = fmaf(eh[d0 + 2], wv4.z, ze);
            ze = fmaf(eh[d0 + 3], wv4.w, ze);
        }
        float zh = 0.f;
        const float* whrow = Wh + lane * 64;
#pragma unroll
        for (int d0 = 0; d0 < 64; d0 += 4) {
            float4 wv4 = *(const float4*)(whrow + d0);
            zh = fmaf(eh[128 + d0 + 0], wv4.x, zh);
            zh = fmaf(eh[128 + d0 + 1], wv4.y, zh);
            zh = fmaf(eh[128 + d0 + 2], wv4.z, zh);
            zh = fmaf(eh[128 + d0 + 3], wv4.w, zh);
        }
        float ssum = wred_sum64(ze + zh);
        float mean = ssum * (1.f / 128.f);
        float sq   = wred_sum64(ze * ze + zh * zh);
        float var  = sq * (1.f / 128.f) - mean * mean;
        float rinv = rsqrtf(var + 1e-5f);
        float oe = (ze - mean) * rinv * gamma[lane] + beta[lane];
        float oh = (zh - mean) * rinv * gamma[64 + lane] + beta[64 + lane];
        out[(size_t)blk * 128 + lane]      = oe;
        out[(size_t)blk * 128 + 64 + lane] = oh;
    }
}

extern "C" void kernel_launch(void* const* d_in, const int* in_sizes, int n_in,
                              void* d_out, int out_size, void* d_ws, size_t ws_size,
                              hipStream_t stream) {
    const float* curr_rho = (const float*)d_in[0];
    const float* curr_hyp = (const float*)d_in[1];
    const float* demo_rho = (const float*)d_in[2];
    const float* demo_hyp = (const float*)d_in[3];
    const float* We       = (const float*)d_in[4];
    const float* Wh       = (const float*)d_in[5];
    const float* gamma    = (const float*)d_in[6];
    const float* beta     = (const float*)d_in[7];
    float* out = (float*)d_out;

    float* ws   = (float*)d_ws;
    float* dH2  = ws;                     // 4096 floats
    float* logv = ws + 4096;              // 262144 floats
    float* part = ws + 4096 + 262144;     // 512*64*196 floats = 25.7 MB

    k_hyp<<<1024, 256, 0, stream>>>(curr_hyp, demo_hyp, dH2, logv);
    k_part<<<512, 512, 0, stream>>>(curr_rho, demo_rho, dH2, logv, part);
    k_merge<<<512, 256, 0, stream>>>(part, curr_hyp, We, Wh, gamma, beta, out);
}

// Round 6
// 255.650 us; speedup vs baseline: 1.0810x; 1.0810x over previous
//
#include <hip/hip_runtime.h>

#define DEV __device__ __forceinline__

constexpr int A_ = 64, DE = 128, M_ = 512, DH = 64;
constexpr int REC = 208;  // floats: [0]=max [1]=sum [16..144)=e128 [144..208)=v64 ; 832 B = 13 lines

DEV float wred_sum64(float v) {
#pragma unroll
    for (int o = 1; o < 64; o <<= 1) v += __shfl_xor(v, o, 64);
    return v;
}

// ---------------- Kernel 1: per-(b,m) hyperbolic dH2 + log_map ----------------
__global__ __launch_bounds__(256) void k_hyp(const float* __restrict__ curr_hyp,
                                             const float* __restrict__ demo_hyp,
                                             float* __restrict__ dH2,
                                             float* __restrict__ logv) {
    const int lane = threadIdx.x & 63;
    const int r    = (blockIdx.x << 2) + (threadIdx.x >> 6);  // [0, B*M)
    const int b    = r >> 9;                                  // M=512

    float x = curr_hyp[(b << 6) + lane];
    float y = demo_hyp[((size_t)r << 6) + lane];
    const float mx = 1.0f - 1e-5f;

    float x2r = wred_sum64(x * x);
    float xn  = fmaxf(sqrtf(x2r), 1e-15f);
    float sx  = xn > mx ? mx / xn : 1.0f;
    x *= sx;
    float x2 = x2r * sx * sx;
    float y2r = wred_sum64(y * y);
    float yn  = fmaxf(sqrtf(y2r), 1e-15f);
    float sy  = yn > mx ? mx / yn : 1.0f;
    y *= sy;
    float y2 = y2r * sy * sy;

    float xy = wred_sum64(x * y);
    float num = (1.f - 2.f * xy + y2) * (-x) + (1.f - x2) * y;
    float den = fmaxf(1.f - 2.f * xy + x2 * y2, 1e-15f);
    float u   = num / den;

    float u2  = wred_sum64(u * u);
    float un  = fmaxf(sqrtf(u2), 1e-15f);
    float arg = fminf(un, 1.f - 1e-7f);
    float at  = 0.5f * __logf((1.f + arg) / (1.f - arg));  // atanh

    if (lane == 0) dH2[r] = 4.f * at * at;

    float lamden = fmaxf(1.f - x2, 1e-15f);  // 2/lambda
    float ls     = lamden * at / un;
    logv[((size_t)r << 6) + lane] = ls * u;
}

// ---------------- Kernel 2: split-K partials with in-block merge ----------------
// grid = b(8) x mc(16) x ag(8) = 1024 blocks, 256 thr = 4 waves.
// Block covers m in [mc*32, mc*32+32), a in [ag*8, ag*8+8); reads 4KB-contiguous rows.
// Wave w handles 8 m's. Lane: h=lane>>5 (a-parity), dc=lane&31 (d-slice 4dc..4dc+4).
// Lane's float4 k covers a_local = 2k+h. Per-lane online state; block-merge in LDS;
// 8 aligned 832B records per block.
__global__ __launch_bounds__(256, 4) void k_part(const float* __restrict__ curr_rho,
                                                 const float* __restrict__ demo_rho,
                                                 const float* __restrict__ dH2,
                                                 const float* __restrict__ logv,
                                                 float* __restrict__ part) {
    __shared__ __align__(16) float lv_lds[32 * 64];   // 8 KB
    __shared__ float dh_lds[32];
    __shared__ __align__(16) float mb[32 * REC];      // 26.6 KB merge buffer

    const int t   = threadIdx.x;
    const int blk = blockIdx.x;
    const int b   = blk >> 7, mc = (blk >> 3) & 15, ag = blk & 7;
    const int lane = t & 63, w = t >> 6;
    const int h = lane >> 5, dc = lane & 31;

    // stage logv[b, mc*32 .. +32, :] (2048 floats) and dH2 chunk
    {
        const float* lsrc = logv + ((size_t)b * M_ + mc * 32) * DH;
        *(float4*)&lv_lds[t * 8]     = *(const float4*)(lsrc + t * 8);
        *(float4*)&lv_lds[t * 8 + 4] = *(const float4*)(lsrc + t * 8 + 4);
        if (t < 32) dh_lds[t] = dH2[b * M_ + mc * 32 + t];
    }

    // q fragments: qf[k] = curr_rho[b, ag*8 + 2k + h, 4dc .. 4dc+4)
    float qf[4][4];
#pragma unroll
    for (int k = 0; k < 4; k++) {
        int a = ag * 8 + 2 * k + h;
        float4 q = *(const float4*)(curr_rho + ((size_t)b * A_ + a) * DE + dc * 4);
        qf[k][0] = q.x; qf[k][1] = q.y; qf[k][2] = q.z; qf[k][3] = q.w;
    }

    float mAcc[4], sAcc[4], eAcc[4][4], vAcc[4][2];
#pragma unroll
    for (int k = 0; k < 4; k++) {
        mAcc[k] = -1e30f; sAcc[k] = 0.f;
        eAcc[k][0] = eAcc[k][1] = eAcc[k][2] = eAcc[k][3] = 0.f;
        vAcc[k][0] = vAcc[k][1] = 0.f;
    }
    __syncthreads();

    // wave w's rows: local m = 8w + i ; global row base:
    const float* rb = demo_rho + (((size_t)b * M_ + mc * 32 + 8 * w) * A_ + ag * 8) * DE;
    const size_t rstride = (size_t)A_ * DE;  // 8192 floats between m-rows

    // 2-deep software pipeline; lane reads float4s {lane, lane+64, lane+128, lane+192}
    float4 c0[4], c1[4];
#pragma unroll
    for (int k = 0; k < 4; k++) {
        c0[k] = *(const float4*)(rb + (size_t)0 * rstride + lane * 4 + k * 256);
        c1[k] = *(const float4*)(rb + (size_t)1 * rstride + lane * 4 + k * 256);
    }

    for (int i = 0; i < 8; ++i) {
        float4 nx[4];
        if (i < 6) {
            const float* nb = rb + (size_t)(i + 2) * rstride;
#pragma unroll
            for (int k = 0; k < 4; k++) nx[k] = *(const float4*)(nb + lane * 4 + k * 256);
        }
        const int row = 8 * w + i;
        float2 lvv = *(const float2*)&lv_lds[row * 64 + dc * 2];
        float dh = dh_lds[row];

        float ps[4];
#pragma unroll
        for (int k = 0; k < 4; k++) {
            float kf[4] = {c0[k].x, c0[k].y, c0[k].z, c0[k].w};
            float p = 0.f;
#pragma unroll
            for (int j = 0; j < 4; j++) { float d = qf[k][j] - kf[j]; p = fmaf(d, d, p); }
            ps[k] = p;
        }
        // half-wave reduce (lanes share h; xor<32 stays in-half)
#pragma unroll
        for (int o = 1; o < 32; o <<= 1) {
#pragma unroll
            for (int k = 0; k < 4; k++) ps[k] += __shfl_xor(ps[k], o, 64);
        }
#pragma unroll
        for (int k = 0; k < 4; k++) {
            float sc = -(dh + ps[k]);
            float nm = fmaxf(mAcc[k], sc);
            float r  = __expf(mAcc[k] - nm);
            float wt = __expf(sc - nm);
            sAcc[k] = sAcc[k] * r + wt;
            eAcc[k][0] = fmaf(eAcc[k][0], r, wt * c0[k].x);
            eAcc[k][1] = fmaf(eAcc[k][1], r, wt * c0[k].y);
            eAcc[k][2] = fmaf(eAcc[k][2], r, wt * c0[k].z);
            eAcc[k][3] = fmaf(eAcc[k][3], r, wt * c0[k].w);
            vAcc[k][0] = fmaf(vAcc[k][0], r, wt * lvv.x);
            vAcc[k][1] = fmaf(vAcc[k][1], r, wt * lvv.y);
            mAcc[k] = nm;
        }
#pragma unroll
        for (int k = 0; k < 4; k++) { c0[k] = c1[k]; c1[k] = nx[k]; }
    }

    // dump wave-partials: slot = w*8 + a_local
#pragma unroll
    for (int k = 0; k < 4; k++) {
        int slot = w * 8 + 2 * k + h;
        *(float4*)&mb[slot * REC + 16 + dc * 4] =
            make_float4(eAcc[k][0], eAcc[k][1], eAcc[k][2], eAcc[k][3]);
        *(float2*)&mb[slot * REC + 144 + dc * 2] = make_float2(vAcc[k][0], vAcc[k][1]);
        if (dc == 0) { mb[slot * REC] = mAcc[k]; mb[slot * REC + 1] = sAcc[k]; }
    }
    __syncthreads();

    // wave w merges a_local in {w, w+4} across the 4 wave-partials; writes record
    for (int al = w; al < 8; al += 4) {
        float m0 = mb[(0 * 8 + al) * REC], m1 = mb[(1 * 8 + al) * REC];
        float m2 = mb[(2 * 8 + al) * REC], m3 = mb[(3 * 8 + al) * REC];
        float g = fmaxf(fmaxf(m0, m1), fmaxf(m2, m3));
        float f0 = __expf(m0 - g), f1 = __expf(m1 - g);
        float f2 = __expf(m2 - g), f3 = __expf(m3 - g);
        float gs = mb[al * REC + 1] * f0 + mb[(8 + al) * REC + 1] * f1 +
                   mb[(16 + al) * REC + 1] * f2 + mb[(24 + al) * REC + 1] * f3;
        float* rec = part + (((size_t)(b * A_ + ag * 8 + al)) * 16 + mc) * REC;
        // e: lane covers comps {2*lane, 2*lane+1}
        float e0 = f0 * mb[al * REC + 16 + 2 * lane] + f1 * mb[(8 + al) * REC + 16 + 2 * lane] +
                   f2 * mb[(16 + al) * REC + 16 + 2 * lane] + f3 * mb[(24 + al) * REC + 16 + 2 * lane];
        float e1 = f0 * mb[al * REC + 17 + 2 * lane] + f1 * mb[(8 + al) * REC + 17 + 2 * lane] +
                   f2 * mb[(16 + al) * REC + 17 + 2 * lane] + f3 * mb[(24 + al) * REC + 17 + 2 * lane];
        *(float2*)&rec[16 + 2 * lane] = make_float2(e0, e1);
        // v: lane covers comp lane
        float vv = f0 * mb[al * REC + 144 + lane] + f1 * mb[(8 + al) * REC + 144 + lane] +
                   f2 * mb[(16 + al) * REC + 144 + lane] + f3 * mb[(24 + al) * REC + 144 + lane];
        rec[144 + lane] = vv;
        if (lane == 0) { rec[0] = g; rec[1] = gs; }
    }
}

// ---------------- Kernel 3: merge 16 partials + epilogue ----------------
// one block per (b,a); 256 thr; records contiguous (16 x 832 B, L2/L3-warm)
__global__ __launch_bounds__(256) void k_merge(const float* __restrict__ part,
                                               const float* __restrict__ curr_hyp,
                                               const float* __restrict__ We,
                                               const float* __restrict__ Wh,
                                               const float* __restrict__ gamma,
                                               const float* __restrict__ beta,
                                               float* __restrict__ out) {
    __shared__ float eh[192];  // [0:128) e_out, [128:192) h
    __shared__ float vv[64];

    const int t = threadIdx.x, w = t >> 6, lane = t & 63;
    const int blk = blockIdx.x, b = blk >> 6;
    const float* pbase = part + (size_t)blk * 16 * REC;

    // every thread computes merge factors (broadcast loads, L2-hot)
    float mk[16];
#pragma unroll
    for (int k = 0; k < 16; k++) mk[k] = pbase[k * REC];
    float g = mk[0];
#pragma unroll
    for (int k = 1; k < 16; k++) g = fmaxf(g, mk[k]);
    float fk[16];
    float gs = 0.f;
#pragma unroll
    for (int k = 0; k < 16; k++) { fk[k] = __expf(mk[k] - g); gs += pbase[k * REC + 1] * fk[k]; }
    const float inv = 1.f / gs;

    if (t < 192) {
        const int off = (t < 128) ? (16 + t) : (144 + (t - 128));
        float acc = 0.f;
#pragma unroll
        for (int k = 0; k < 16; k++) acc = fmaf(pbase[k * REC + off], fk[k], acc);
        acc *= inv;
        if (t < 128) eh[t] = acc;
        else vv[t - 128] = acc;
    }
    __syncthreads();

    if (w == 0) {
        float v = vv[lane];
        const float mxb = 1.0f - 1e-5f;
        float x = curr_hyp[(b << 6) + lane];
        float x2r = wred_sum64(x * x);
        float xn  = fmaxf(sqrtf(x2r), 1e-15f);
        float sx  = xn > mxb ? mxb / xn : 1.f;
        x *= sx;
        float x2 = x2r * sx * sx;
        float lamden = fmaxf(1.f - x2, 1e-15f);  // 2/lambda

        float v2 = wred_sum64(v * v);
        float vn = fmaxf(sqrtf(v2), 1e-15f);
        float targ   = vn / lamden;              // lambda*vnorm/2
        float e2     = __expf(2.f * targ);
        float factor = 1.f - 2.f / (e2 + 1.f);   // tanh, inf-safe
        float wvv    = v * (factor / vn);

        float w2 = wred_sum64(wvv * wvv);
        float xw = wred_sum64(x * wvv);
        float num = (1.f + 2.f * xw + w2) * x + (1.f - x2) * wvv;
        float den = fmaxf(1.f + 2.f * xw + x2 * w2, 1e-15f);
        float hq  = num / den;
        float h2  = wred_sum64(hq * hq);
        float hn  = fmaxf(sqrtf(h2), 1e-15f);
        float shh = hn > mxb ? mxb / hn : 1.f;
        hq *= shh;
        eh[128 + lane] = hq;  // same-wave visibility

        float ze = 0.f;
        const float* werow = We + lane * 128;
#pragma unroll
        for (int d0 = 0; d0 < 128; d0 += 4) {
            float4 wv4 = *(const float4*)(werow + d0);
            ze = fmaf(eh[d0 + 0], wv4.x, ze);
            ze = fmaf(eh[d0 + 1], wv4.y, ze);
            ze = fmaf(eh[d0 + 2], wv4.z, ze);
            ze = fmaf(eh[d0 + 3], wv4.w, ze);
        }
        float zh = 0.f;
        const float* whrow = Wh + lane * 64;
#pragma unroll
        for (int d0 = 0; d0 < 64; d0 += 4) {
            float4 wv4 = *(const float4*)(whrow + d0);
            zh = fmaf(eh[128 + d0 + 0], wv4.x, zh);
            zh = fmaf(eh[128 + d0 + 1], wv4.y, zh);
            zh = fmaf(eh[128 + d0 + 2], wv4.z, zh);
            zh = fmaf(eh[128 + d0 + 3], wv4.w, zh);
        }
        float ssum = wred_sum64(ze + zh);
        float mean = ssum * (1.f / 128.f);
        float sq   = wred_sum64(ze * ze + zh * zh);
        float var  = sq * (1.f / 128.f) - mean * mean;
        float rinv = rsqrtf(var + 1e-5f);
        float oe = (ze - mean) * rinv * gamma[lane] + beta[lane];
        float oh = (zh - mean) * rinv * gamma[64 + lane] + beta[64 + lane];
        out[(size_t)blk * 128 + lane]      = oe;
        out[(size_t)blk * 128 + 64 + lane] = oh;
    }
}

extern "C" void kernel_launch(void* const* d_in, const int* in_sizes, int n_in,
                              void* d_out, int out_size, void* d_ws, size_t ws_size,
                              hipStream_t stream) {
    const float* curr_rho = (const float*)d_in[0];
    const float* curr_hyp = (const float*)d_in[1];
    const float* demo_rho = (const float*)d_in[2];
    const float* demo_hyp = (const float*)d_in[3];
    const float* We       = (const float*)d_in[4];
    const float* Wh       = (const float*)d_in[5];
    const float* gamma    = (const float*)d_in[6];
    const float* beta     = (const float*)d_in[7];
    float* out = (float*)d_out;

    float* ws   = (float*)d_ws;
    float* dH2  = ws;                     // 4096 floats
    float* logv = ws + 4096;              // 262144 floats
    float* part = ws + 4096 + 262144;     // 512*16*208 floats = 6.8 MB (64B-aligned)

    k_hyp<<<1024, 256, 0, stream>>>(curr_hyp, demo_hyp, dH2, logv);
    k_part<<<1024, 256, 0, stream>>>(curr_rho, demo_rho, dH2, logv, part);
    k_merge<<<512, 256, 0, stream>>>(part, curr_hyp, We, Wh, gamma, beta, out);
}